// Round 10
// baseline (551.367 us; speedup 1.0000x reference)
//
#include <hip/hip_runtime.h>
#include <hip/hip_bf16.h>
#include <stdint.h>

typedef __bf16 v8bf __attribute__((ext_vector_type(8)));
typedef short v4s __attribute__((ext_vector_type(4)));
typedef float f32x4 __attribute__((ext_vector_type(4)));

__device__ __forceinline__ void gload_lds16(const void* g, void* l) {
    __builtin_amdgcn_global_load_lds(
        (const __attribute__((address_space(1))) void*)g,
        (__attribute__((address_space(3))) void*)l, 16, 0, 0);
}

__device__ __forceinline__ unsigned short f2bf(float f) {
    __hip_bfloat16 h = __float2bfloat16(f);
    return __builtin_bit_cast(unsigned short, h);
}

// K=16 bf16 MFMA: D = A*B + C. A,B = 4 bf16 (2 VGPRs).
// A layout: A[m=lane&15][k=(lane>>4)*4 + j]  == C/D layout of a prior MFMA.
__device__ __forceinline__ f32x4 mfma16x16x16bf(v4s a, v4s b, f32x4 c) {
#if __has_builtin(__builtin_amdgcn_mfma_f32_16x16x16bf16_1k)
    return __builtin_amdgcn_mfma_f32_16x16x16bf16_1k(a, b, c, 0, 0, 0);
#elif __has_builtin(__builtin_amdgcn_mfma_f32_16x16x16_bf16)
    return __builtin_amdgcn_mfma_f32_16x16x16_bf16(a, b, c, 0, 0, 0);
#else
    // asm fallback: defensive nops cover VALU->MFMA and MFMA->reader hazards
    asm("s_nop 1\n\t"
        "v_mfma_f32_16x16x16_bf16 %0, %1, %2, %0\n\t"
        "s_nop 7\n\ts_nop 3"
        : "+v"(c) : "v"(a), "v"(b));
    return c;
#endif
}

// ---- fused conversion: xc = concat(x,c) bf16 [8][2048][512]; Wbf = 4 weights
__global__ __launch_bounds__(256) void cvt_xcw(const float* __restrict__ x,
                                               const float* __restrict__ c,
                                               const float* __restrict__ wq,
                                               const float* __restrict__ wk,
                                               const float* __restrict__ wv,
                                               const float* __restrict__ wp,
                                               __hip_bfloat16* __restrict__ xc,
                                               __hip_bfloat16* __restrict__ wout) {
    int bid = blockIdx.x;
    if (bid < 8192) {
        int i = bid * 256 + threadIdx.x;
        long e = (long)i * 4;
        int b = (int)(e >> 20);
        int rem = (int)(e & ((1 << 20) - 1));
        int r = rem >> 9;
        int col = rem & 511;
        const float* src = (r < 1024) ? (x + ((long)b << 19) + (long)r * 512 + col)
                                      : (c + ((long)b << 19) + (long)(r - 1024) * 512 + col);
        float4 v = *(const float4*)src;
        ushort4 o;
        o.x = f2bf(v.x); o.y = f2bf(v.y); o.z = f2bf(v.z); o.w = f2bf(v.w);
        ((ushort4*)xc)[i] = o;
    } else {
        int i = (bid - 8192) * 256 + threadIdx.x;
        int e = i * 4;
        int w = e >> 18;
        int off = e & ((1 << 18) - 1);
        const float* src = (w == 0 ? wq : w == 1 ? wk : w == 2 ? wv : wp) + off;
        float4 val = *(const float4*)src;
        ushort4 o;
        o.x = f2bf(val.x); o.y = f2bf(val.y); o.z = f2bf(val.z); o.w = f2bf(val.w);
        ((ushort4*)wout)[i] = o;
    }
}

// mask int32 [8][1024][2048] -> bit-packed TRANSPOSED uint64 [8][word 32][q 1024]
__global__ __launch_bounds__(256) void cvt_mask(const int* __restrict__ mask,
                                                unsigned long long* __restrict__ mbt) {
    int t = threadIdx.x;
    long base = (long)blockIdx.x * 1024;
#pragma unroll
    for (int j = 0; j < 4; j++) {
        long i = base + j * 256 + t;            // [b][q][key] linear
        int v = mask[i] != 0;
        unsigned long long bits = __ballot(v);
        if ((t & 63) == 0) {
            int b = (int)(i >> 21);
            int q = (int)((i >> 11) & 1023);
            int word = (int)((i >> 6) & 31);
            mbt[((long)b * 32 + word) * 1024 + q] = bits;
        }
    }
}

// ---- fused QKV projection GEMM ------------------------------------------
// C[m,n] = sum_k xc[m,k]*Wbf[n,k], M=16384, N=1536. by<8: Q/K head-split
// scatter; Q pre-scaled by 0.125*log2e (softmax scale folded, exp2 path).
// by>=8 (V): LDS transpose -> coalesced V^T stores.
__global__ __launch_bounds__(256) void gemm_qkv(const __hip_bfloat16* __restrict__ A,
                                                const __hip_bfloat16* __restrict__ Bw,
                                                __hip_bfloat16* __restrict__ Qw,
                                                __hip_bfloat16* __restrict__ Kw,
                                                __hip_bfloat16* __restrict__ Vtw) {
    __shared__ union {
        struct { __hip_bfloat16 As[128 * 32]; __hip_bfloat16 Bs[128 * 32]; } s;
        __hip_bfloat16 T[128 * 136];
    } u;
    const int tid = threadIdx.x;
    const int wave = tid >> 6, lane = tid & 63;
    const int m0 = blockIdx.x * 128, n0 = blockIdx.y * 128;

    const int la = lane >> 2;
    const int kc = (lane & 3) * 8;
    const long ga0 = (long)(m0 + wave * 16 + la) * 512 + kc;
    const long ga1 = (long)(m0 + (wave + 4) * 16 + la) * 512 + kc;
    const long gb0 = (long)(n0 + wave * 16 + la) * 512 + kc;
    const long gb1 = (long)(n0 + (wave + 4) * 16 + la) * 512 + kc;

    f32x4 acc[4][4] = {};
    const int mw = (wave & 1) * 64, nw = (wave >> 1) * 64;
    const int lrow = lane & 15, lk = (lane >> 4) * 8;

    for (int k0 = 0; k0 < 512; k0 += 32) {
        gload_lds16(A + ga0 + k0, &u.s.As[wave * 512]);
        gload_lds16(A + ga1 + k0, &u.s.As[(wave + 4) * 512]);
        gload_lds16(Bw + gb0 + k0, &u.s.Bs[wave * 512]);
        gload_lds16(Bw + gb1 + k0, &u.s.Bs[(wave + 4) * 512]);
        __syncthreads();
        v8bf a[4], b[4];
#pragma unroll
        for (int i = 0; i < 4; i++) {
            a[i] = *(const v8bf*)&u.s.As[(mw + i * 16 + lrow) * 32 + lk];
            b[i] = *(const v8bf*)&u.s.Bs[(nw + i * 16 + lrow) * 32 + lk];
        }
#pragma unroll
        for (int mi = 0; mi < 4; mi++)
#pragma unroll
            for (int ni = 0; ni < 4; ni++)
                acc[mi][ni] = __builtin_amdgcn_mfma_f32_16x16x32_bf16(a[mi], b[ni], acc[mi][ni], 0, 0, 0);
        __syncthreads();
    }

    const int lq = lane >> 4;
    if (blockIdx.y < 8) {
#pragma unroll
        for (int mi = 0; mi < 4; mi++)
#pragma unroll
            for (int ni = 0; ni < 4; ni++)
#pragma unroll
                for (int r = 0; r < 4; r++) {
                    int grow = m0 + mw + mi * 16 + lq * 4 + r;
                    int gcol = n0 + nw + ni * 16 + lrow;
                    int w = gcol >> 9, g9 = gcol & 511;
                    int h = g9 >> 6, dh = g9 & 63;
                    int b_ = grow >> 11, rr = grow & 2047;
                    float val = acc[mi][ni][r];
                    if (w == 0) {
                        if (rr < 1024)
                            Qw[((long)(b_ * 8 + h) * 1024 + rr) * 64 + dh] =
                                __float2bfloat16(val * 0.1803368801f);  // 0.125*log2(e)
                    } else {
                        Kw[((long)(b_ * 8 + h) * 2048 + rr) * 64 + dh] = __float2bfloat16(val);
                    }
                }
    } else {
#pragma unroll
        for (int mi = 0; mi < 4; mi++)
#pragma unroll
            for (int ni = 0; ni < 4; ni++) {
                int n_l = nw + ni * 16 + lrow;
                int m_l = mw + mi * 16 + lq * 4;
                ushort4 pk;
                pk.x = f2bf(acc[mi][ni][0]); pk.y = f2bf(acc[mi][ni][1]);
                pk.z = f2bf(acc[mi][ni][2]); pk.w = f2bf(acc[mi][ni][3]);
                *(ushort4*)&u.T[n_l * 136 + m_l] = pk;
            }
        __syncthreads();
        const int no = (blockIdx.y - 8) * 128;
        const int b_ = m0 >> 11, rrb = m0 & 2047;
#pragma unroll
        for (int i = 0; i < 8; i++) {
            int s = tid + i * 256;
            int n_l = s >> 4, ch = s & 15;
            int ng = no + n_l;
            int h = ng >> 6, dh = ng & 63;
            uint4 v = *(const uint4*)&u.T[n_l * 136 + ch * 8];
            *(uint4*)&Vtw[((long)(b_ * 8 + h) * 64 + dh) * 2048 + rrb + ch * 8] = v;
        }
    }
}

// ---- output projection GEMM: d_out[m,n] = sum_k Yb[m,k]*Wp[n,k], fp32 out
__global__ __launch_bounds__(256) void gemm_out(const __hip_bfloat16* __restrict__ A,
                                                const __hip_bfloat16* __restrict__ Bw,
                                                float* __restrict__ outp) {
    __shared__ __hip_bfloat16 As[128 * 32];
    __shared__ __hip_bfloat16 Bs[128 * 32];
    const int tid = threadIdx.x;
    const int wave = tid >> 6, lane = tid & 63;
    const int m0 = blockIdx.x * 128, n0 = blockIdx.y * 128;

    const int la = lane >> 2;
    const int kc = (lane & 3) * 8;
    const long ga0 = (long)(m0 + wave * 16 + la) * 512 + kc;
    const long ga1 = (long)(m0 + (wave + 4) * 16 + la) * 512 + kc;
    const long gb0 = (long)(n0 + wave * 16 + la) * 512 + kc;
    const long gb1 = (long)(n0 + (wave + 4) * 16 + la) * 512 + kc;

    f32x4 acc[4][4] = {};
    const int mw = (wave & 1) * 64, nw = (wave >> 1) * 64;
    const int lrow = lane & 15, lk = (lane >> 4) * 8;

    for (int k0 = 0; k0 < 512; k0 += 32) {
        gload_lds16(A + ga0 + k0, &As[wave * 512]);
        gload_lds16(A + ga1 + k0, &As[(wave + 4) * 512]);
        gload_lds16(Bw + gb0 + k0, &Bs[wave * 512]);
        gload_lds16(Bw + gb1 + k0, &Bs[(wave + 4) * 512]);
        __syncthreads();
        v8bf a[4], b[4];
#pragma unroll
        for (int i = 0; i < 4; i++) {
            a[i] = *(const v8bf*)&As[(mw + i * 16 + lrow) * 32 + lk];
            b[i] = *(const v8bf*)&Bs[(nw + i * 16 + lrow) * 32 + lk];
        }
#pragma unroll
        for (int mi = 0; mi < 4; mi++)
#pragma unroll
            for (int ni = 0; ni < 4; ni++)
                acc[mi][ni] = __builtin_amdgcn_mfma_f32_16x16x32_bf16(a[mi], b[ni], acc[mi][ni], 0, 0, 0);
        __syncthreads();
    }

    const int lq = lane >> 4;
#pragma unroll
    for (int mi = 0; mi < 4; mi++)
#pragma unroll
        for (int ni = 0; ni < 4; ni++)
#pragma unroll
            for (int r = 0; r < 4; r++) {
                int grow = m0 + mw + mi * 16 + lq * 4 + r;
                int gcol = n0 + nw + ni * 16 + lrow;
                outp[(long)grow * 512 + gcol] = acc[mi][ni][r];
            }
}

// ---- flash attention v5: barrier-free, LDS-free register pipeline --------
// grid 1024 (b=L&7 XCD-pinned, qt=(L>>3)&15, h=L>>7). 4 waves, wave owns
// 16 q rows end-to-end. Per 16-key chunk: S^T = K·Q^T (2x 16x16x32 MFMA,
// C[key][q]) -> exp2+mask in regs -> P is ALREADY in 16x16x16 A-layout
// (A[m=q=lane&15][k=key=quad*4+j]) -> 4x 16x16x16 PV MFMA into O[16q][64d].
// No LDS, no barriers, no cross-wave reduction. K/V/mask addresses are
// wave-invariant -> 4x L1 reuse per block.
__global__ __launch_bounds__(256) void flash(const __hip_bfloat16* __restrict__ Q,
                                             const __hip_bfloat16* __restrict__ K,
                                             const __hip_bfloat16* __restrict__ Vt,
                                             const unsigned long long* __restrict__ Mbt,
                                             __hip_bfloat16* __restrict__ Y) {
    const int L = blockIdx.x;
    const int b = L & 7, qt = (L >> 3) & 15, h = L >> 7;
    const int bh = b * 8 + h;
    const int tid = threadIdx.x, w = tid >> 6, lane = tid & 63;
    const int lcol = lane & 15, lq = lane >> 4;

    const __hip_bfloat16* Qp = Q + ((long)bh * 1024 + qt * 64 + w * 16 + lcol) * 64 + lq * 8;
    const __hip_bfloat16* Kp = K + (long)bh * 2048 * 64 + lcol * 64 + lq * 8;
    const __hip_bfloat16* Vp = Vt + ((long)bh * 64 + lcol) * 2048 + lq * 4;
    const unsigned long long* Mp = Mbt + (long)b * 32 * 1024 + qt * 64 + w * 16 + lcol;

    // Q B-frags (wave's 16 q rows), pre-scaled by 0.125*log2e
    v8bf bq0 = *(const v8bf*)(Qp);
    v8bf bq1 = *(const v8bf*)(Qp + 32);

    f32x4 O[4] = {};
    float lsum = 0.f;
    const int msh = lq * 4;

    for (int kt = 0; kt < 16; kt++) {
        unsigned long long w0 = Mp[(long)(kt * 2) * 1024];
        unsigned long long w1 = Mp[(long)(kt * 2 + 1) * 1024];
#pragma unroll
        for (int ch = 0; ch < 8; ch++) {
            const int kb = kt * 128 + ch * 16;
            // K A-frags: A[m=key=kb+lcol][k=d]
            v8bf ak0 = *(const v8bf*)(Kp + (long)kb * 64);
            v8bf ak1 = *(const v8bf*)(Kp + (long)kb * 64 + 32);
            // V B-frags: B[n=d=nd*16+lcol][k=key=kb+lq*4+j]
            v4s vv0 = *(const v4s*)(Vp + kb);
            v4s vv1 = *(const v4s*)(Vp + 16 * 2048 + kb);
            v4s vv2 = *(const v4s*)(Vp + 32 * 2048 + kb);
            v4s vv3 = *(const v4s*)(Vp + 48 * 2048 + kb);
            // S^T[key][q] (C: row=key=lq*4+r, col=q=lcol)
            f32x4 st = {};
            st = __builtin_amdgcn_mfma_f32_16x16x32_bf16(ak0, bq0, st, 0, 0, 0);
            st = __builtin_amdgcn_mfma_f32_16x16x32_bf16(ak1, bq1, st, 0, 0, 0);
            // mask nibble for (q=lcol, keys kb+lq*4+[0,4))
            unsigned long long mword = (ch < 4) ? w0 : w1;
            unsigned int nib = (unsigned int)(mword >> ((ch & 3) * 16 + msh)) & 0xFu;
            float e0 = ((nib >> 0) & 1u) ? 0.f : __builtin_amdgcn_exp2f(fminf(st[0], 57.f));
            float e1 = ((nib >> 1) & 1u) ? 0.f : __builtin_amdgcn_exp2f(fminf(st[1], 57.f));
            float e2 = ((nib >> 2) & 1u) ? 0.f : __builtin_amdgcn_exp2f(fminf(st[2], 57.f));
            float e3 = ((nib >> 3) & 1u) ? 0.f : __builtin_amdgcn_exp2f(fminf(st[3], 57.f));
            lsum += (e0 + e1) + (e2 + e3);
            // pack P to bf16x4: element j = key kb+lq*4+j  (A-layout for K=16 MFMA)
            __hip_bfloat162 lo = __float22bfloat162_rn(make_float2(e0, e1));
            __hip_bfloat162 hi = __float22bfloat162_rn(make_float2(e2, e3));
            uint2 pku;
            __builtin_memcpy(&pku.x, &lo, 4);
            __builtin_memcpy(&pku.y, &hi, 4);
            v4s pa = __builtin_bit_cast(v4s, pku);
            // PV: O[q][d] += P[q][key16] * V[key16][d]
            O[0] = mfma16x16x16bf(pa, vv0, O[0]);
            O[1] = mfma16x16x16bf(pa, vv1, O[1]);
            O[2] = mfma16x16x16bf(pa, vv2, O[2]);
            O[3] = mfma16x16x16bf(pa, vv3, O[3]);
        }
    }

    // row-sum: reduce over lq groups (all lanes with same lcol)
    float s = lsum;
    s += __shfl_xor(s, 16);
    s += __shfl_xor(s, 32);
    // O C-layout rows are q = lq*4 + r; fetch matching 1/sum via shuffle
    float inv[4];
#pragma unroll
    for (int r = 0; r < 4; r++) inv[r] = 1.f / __shfl(s, lq * 4 + r);

    __hip_bfloat16* Yp = Y + ((long)b * 1024 + qt * 64 + w * 16) * 512 + h * 64 + lcol;
#pragma unroll
    for (int nd = 0; nd < 4; nd++)
#pragma unroll
        for (int r = 0; r < 4; r++)
            Yp[(long)(lq * 4 + r) * 512 + nd * 16] = __float2bfloat16(O[nd][r] * inv[r]);
}

// ---- launch -------------------------------------------------------------
extern "C" void kernel_launch(void* const* d_in, const int* in_sizes, int n_in,
                              void* d_out, int out_size, void* d_ws, size_t ws_size,
                              hipStream_t stream) {
    const float* x = (const float*)d_in[0];
    const float* c = (const float*)d_in[1];
    const int* mask = (const int*)d_in[2];
    const float* Wq = (const float*)d_in[3];
    const float* Wk = (const float*)d_in[4];
    const float* Wv = (const float*)d_in[5];
    const float* Wp = (const float*)d_in[6];

    char* ws = (char*)d_ws;
    __hip_bfloat16* xc  = (__hip_bfloat16*)(ws);                 // 16 MB (dead after gemm_qkv)
    __hip_bfloat16* Wbf = (__hip_bfloat16*)(ws + 16777216);      //  2 MB
    __hip_bfloat16* Qw  = (__hip_bfloat16*)(ws + 18874368);      //  8 MB
    __hip_bfloat16* Kw  = (__hip_bfloat16*)(ws + 27262976);      // 16 MB
    __hip_bfloat16* Vtw = (__hip_bfloat16*)(ws + 44040192);      // 16 MB
    __hip_bfloat16* Yb  = (__hip_bfloat16*)(ws + 60817408);      //  8 MB
    unsigned long long* Mbp = (unsigned long long*)(ws);         //  2 MB, aliases dead xc

    cvt_xcw<<<9216, 256, 0, stream>>>(x, c, Wq, Wk, Wv, Wp, xc, Wbf);
    gemm_qkv<<<dim3(128, 12), 256, 0, stream>>>(xc, Wbf, Qw, Kw, Vtw);
    cvt_mask<<<16384, 256, 0, stream>>>(mask, Mbp);   // after gemm_qkv: overwrites xc
    flash<<<1024, 256, 0, stream>>>(Qw, Kw, Vtw, Mbp, Yb);
    gemm_out<<<dim3(64, 4), 256, 0, stream>>>(Yb, Wbf + 3 * 262144, (float*)d_out);
}

// Round 11
// 288.228 us; speedup vs baseline: 1.9130x; 1.9130x over previous
//
#include <hip/hip_runtime.h>
#include <hip/hip_bf16.h>
#include <stdint.h>

typedef __bf16 v8bf __attribute__((ext_vector_type(8)));
typedef short v4s __attribute__((ext_vector_type(4)));
typedef float f32x4 __attribute__((ext_vector_type(4)));

__device__ __forceinline__ void gload_lds16(const void* g, void* l) {
    __builtin_amdgcn_global_load_lds(
        (const __attribute__((address_space(1))) void*)g,
        (__attribute__((address_space(3))) void*)l, 16, 0, 0);
}

__device__ __forceinline__ unsigned short f2bf(float f) {
    __hip_bfloat16 h = __float2bfloat16(f);
    return __builtin_bit_cast(unsigned short, h);
}

// K=16 bf16 MFMA: D = A*B + C. A,B = 4 bf16 (2 VGPRs).
// A layout: A[m=lane&15][k=(lane>>4)*4 + j]  == C/D layout of a prior MFMA.
__device__ __forceinline__ f32x4 mfma16x16x16bf(v4s a, v4s b, f32x4 c) {
#if __has_builtin(__builtin_amdgcn_mfma_f32_16x16x16bf16_1k)
    return __builtin_amdgcn_mfma_f32_16x16x16bf16_1k(a, b, c, 0, 0, 0);
#elif __has_builtin(__builtin_amdgcn_mfma_f32_16x16x16_bf16)
    return __builtin_amdgcn_mfma_f32_16x16x16_bf16(a, b, c, 0, 0, 0);
#else
    asm("s_nop 1\n\t"
        "v_mfma_f32_16x16x16_bf16 %0, %1, %2, %0\n\t"
        "s_nop 7\n\ts_nop 3"
        : "+v"(c) : "v"(a), "v"(b));
    return c;
#endif
}

// ---- fused conversion: xc = concat(x,c) bf16 [8][2048][512]; Wbf = 4 weights
__global__ __launch_bounds__(256) void cvt_xcw(const float* __restrict__ x,
                                               const float* __restrict__ c,
                                               const float* __restrict__ wq,
                                               const float* __restrict__ wk,
                                               const float* __restrict__ wv,
                                               const float* __restrict__ wp,
                                               __hip_bfloat16* __restrict__ xc,
                                               __hip_bfloat16* __restrict__ wout) {
    int bid = blockIdx.x;
    if (bid < 8192) {
        int i = bid * 256 + threadIdx.x;
        long e = (long)i * 4;
        int b = (int)(e >> 20);
        int rem = (int)(e & ((1 << 20) - 1));
        int r = rem >> 9;
        int col = rem & 511;
        const float* src = (r < 1024) ? (x + ((long)b << 19) + (long)r * 512 + col)
                                      : (c + ((long)b << 19) + (long)(r - 1024) * 512 + col);
        float4 v = *(const float4*)src;
        ushort4 o;
        o.x = f2bf(v.x); o.y = f2bf(v.y); o.z = f2bf(v.z); o.w = f2bf(v.w);
        ((ushort4*)xc)[i] = o;
    } else {
        int i = (bid - 8192) * 256 + threadIdx.x;
        int e = i * 4;
        int w = e >> 18;
        int off = e & ((1 << 18) - 1);
        const float* src = (w == 0 ? wq : w == 1 ? wk : w == 2 ? wv : wp) + off;
        float4 val = *(const float4*)src;
        ushort4 o;
        o.x = f2bf(val.x); o.y = f2bf(val.y); o.z = f2bf(val.z); o.w = f2bf(val.w);
        ((ushort4*)wout)[i] = o;
    }
}

// mask int32 [8][1024][2048] -> bit-packed TRANSPOSED uint64 [8][word 32][q 1024]
__global__ __launch_bounds__(256) void cvt_mask(const int* __restrict__ mask,
                                                unsigned long long* __restrict__ mbt) {
    int t = threadIdx.x;
    long base = (long)blockIdx.x * 1024;
#pragma unroll
    for (int j = 0; j < 4; j++) {
        long i = base + j * 256 + t;            // [b][q][key] linear
        int v = mask[i] != 0;
        unsigned long long bits = __ballot(v);
        if ((t & 63) == 0) {
            int b = (int)(i >> 21);
            int q = (int)((i >> 11) & 1023);
            int word = (int)((i >> 6) & 31);
            mbt[((long)b * 32 + word) * 1024 + q] = bits;
        }
    }
}

// ---- fused QKV projection GEMM ------------------------------------------
// C[m,n] = sum_k xc[m,k]*Wbf[n,k], M=16384, N=1536. by<8: Q/K head-split
// scatter; Q pre-scaled by 0.125*log2e (softmax scale folded, exp2 path).
// by>=8 (V): LDS transpose -> coalesced V^T stores.
__global__ __launch_bounds__(256) void gemm_qkv(const __hip_bfloat16* __restrict__ A,
                                                const __hip_bfloat16* __restrict__ Bw,
                                                __hip_bfloat16* __restrict__ Qw,
                                                __hip_bfloat16* __restrict__ Kw,
                                                __hip_bfloat16* __restrict__ Vtw) {
    __shared__ union {
        struct { __hip_bfloat16 As[128 * 32]; __hip_bfloat16 Bs[128 * 32]; } s;
        __hip_bfloat16 T[128 * 136];
    } u;
    const int tid = threadIdx.x;
    const int wave = tid >> 6, lane = tid & 63;
    const int m0 = blockIdx.x * 128, n0 = blockIdx.y * 128;

    const int la = lane >> 2;
    const int kc = (lane & 3) * 8;
    const long ga0 = (long)(m0 + wave * 16 + la) * 512 + kc;
    const long ga1 = (long)(m0 + (wave + 4) * 16 + la) * 512 + kc;
    const long gb0 = (long)(n0 + wave * 16 + la) * 512 + kc;
    const long gb1 = (long)(n0 + (wave + 4) * 16 + la) * 512 + kc;

    f32x4 acc[4][4] = {};
    const int mw = (wave & 1) * 64, nw = (wave >> 1) * 64;
    const int lrow = lane & 15, lk = (lane >> 4) * 8;

    for (int k0 = 0; k0 < 512; k0 += 32) {
        gload_lds16(A + ga0 + k0, &u.s.As[wave * 512]);
        gload_lds16(A + ga1 + k0, &u.s.As[(wave + 4) * 512]);
        gload_lds16(Bw + gb0 + k0, &u.s.Bs[wave * 512]);
        gload_lds16(Bw + gb1 + k0, &u.s.Bs[(wave + 4) * 512]);
        __syncthreads();
        v8bf a[4], b[4];
#pragma unroll
        for (int i = 0; i < 4; i++) {
            a[i] = *(const v8bf*)&u.s.As[(mw + i * 16 + lrow) * 32 + lk];
            b[i] = *(const v8bf*)&u.s.Bs[(nw + i * 16 + lrow) * 32 + lk];
        }
#pragma unroll
        for (int mi = 0; mi < 4; mi++)
#pragma unroll
            for (int ni = 0; ni < 4; ni++)
                acc[mi][ni] = __builtin_amdgcn_mfma_f32_16x16x32_bf16(a[mi], b[ni], acc[mi][ni], 0, 0, 0);
        __syncthreads();
    }

    const int lq = lane >> 4;
    if (blockIdx.y < 8) {
#pragma unroll
        for (int mi = 0; mi < 4; mi++)
#pragma unroll
            for (int ni = 0; ni < 4; ni++)
#pragma unroll
                for (int r = 0; r < 4; r++) {
                    int grow = m0 + mw + mi * 16 + lq * 4 + r;
                    int gcol = n0 + nw + ni * 16 + lrow;
                    int w = gcol >> 9, g9 = gcol & 511;
                    int h = g9 >> 6, dh = g9 & 63;
                    int b_ = grow >> 11, rr = grow & 2047;
                    float val = acc[mi][ni][r];
                    if (w == 0) {
                        if (rr < 1024)
                            Qw[((long)(b_ * 8 + h) * 1024 + rr) * 64 + dh] =
                                __float2bfloat16(val * 0.1803368801f);  // 0.125*log2(e)
                    } else {
                        Kw[((long)(b_ * 8 + h) * 2048 + rr) * 64 + dh] = __float2bfloat16(val);
                    }
                }
    } else {
#pragma unroll
        for (int mi = 0; mi < 4; mi++)
#pragma unroll
            for (int ni = 0; ni < 4; ni++) {
                int n_l = nw + ni * 16 + lrow;
                int m_l = mw + mi * 16 + lq * 4;
                ushort4 pk;
                pk.x = f2bf(acc[mi][ni][0]); pk.y = f2bf(acc[mi][ni][1]);
                pk.z = f2bf(acc[mi][ni][2]); pk.w = f2bf(acc[mi][ni][3]);
                *(ushort4*)&u.T[n_l * 136 + m_l] = pk;
            }
        __syncthreads();
        const int no = (blockIdx.y - 8) * 128;
        const int b_ = m0 >> 11, rrb = m0 & 2047;
#pragma unroll
        for (int i = 0; i < 8; i++) {
            int s = tid + i * 256;
            int n_l = s >> 4, ch = s & 15;
            int ng = no + n_l;
            int h = ng >> 6, dh = ng & 63;
            uint4 v = *(const uint4*)&u.T[n_l * 136 + ch * 8];
            *(uint4*)&Vtw[((long)(b_ * 8 + h) * 64 + dh) * 2048 + rrb + ch * 8] = v;
        }
    }
}

// ---- output projection GEMM: d_out[m,n] = sum_k Yb[m,k]*Wp[n,k], fp32 out
__global__ __launch_bounds__(256) void gemm_out(const __hip_bfloat16* __restrict__ A,
                                                const __hip_bfloat16* __restrict__ Bw,
                                                float* __restrict__ outp) {
    __shared__ __hip_bfloat16 As[128 * 32];
    __shared__ __hip_bfloat16 Bs[128 * 32];
    const int tid = threadIdx.x;
    const int wave = tid >> 6, lane = tid & 63;
    const int m0 = blockIdx.x * 128, n0 = blockIdx.y * 128;

    const int la = lane >> 2;
    const int kc = (lane & 3) * 8;
    const long ga0 = (long)(m0 + wave * 16 + la) * 512 + kc;
    const long ga1 = (long)(m0 + (wave + 4) * 16 + la) * 512 + kc;
    const long gb0 = (long)(n0 + wave * 16 + la) * 512 + kc;
    const long gb1 = (long)(n0 + (wave + 4) * 16 + la) * 512 + kc;

    f32x4 acc[4][4] = {};
    const int mw = (wave & 1) * 64, nw = (wave >> 1) * 64;
    const int lrow = lane & 15, lk = (lane >> 4) * 8;

    for (int k0 = 0; k0 < 512; k0 += 32) {
        gload_lds16(A + ga0 + k0, &As[wave * 512]);
        gload_lds16(A + ga1 + k0, &As[(wave + 4) * 512]);
        gload_lds16(Bw + gb0 + k0, &Bs[wave * 512]);
        gload_lds16(Bw + gb1 + k0, &Bs[(wave + 4) * 512]);
        __syncthreads();
        v8bf a[4], b[4];
#pragma unroll
        for (int i = 0; i < 4; i++) {
            a[i] = *(const v8bf*)&As[(mw + i * 16 + lrow) * 32 + lk];
            b[i] = *(const v8bf*)&Bs[(nw + i * 16 + lrow) * 32 + lk];
        }
#pragma unroll
        for (int mi = 0; mi < 4; mi++)
#pragma unroll
            for (int ni = 0; ni < 4; ni++)
                acc[mi][ni] = __builtin_amdgcn_mfma_f32_16x16x32_bf16(a[mi], b[ni], acc[mi][ni], 0, 0, 0);
        __syncthreads();
    }

    const int lq = lane >> 4;
#pragma unroll
    for (int mi = 0; mi < 4; mi++)
#pragma unroll
        for (int ni = 0; ni < 4; ni++)
#pragma unroll
            for (int r = 0; r < 4; r++) {
                int grow = m0 + mw + mi * 16 + lq * 4 + r;
                int gcol = n0 + nw + ni * 16 + lrow;
                outp[(long)grow * 512 + gcol] = acc[mi][ni][r];
            }
}

// ---- flash attention v6: LDS-staged K/V + register-chained P -------------
// grid 1024 (b=L&7 XCD-pinned, qt=(L>>3)&15, h=L>>7). 4 waves; wave owns
// 16 q rows end-to-end (own lsum, own O). Per 64-key tile: coalesced uint4
// staging of K [64k][64d] and V^T [64d][64k] into padded LDS; per 16-key
// subtile: S^T = K·Q^T (A-frags ds_read_b128 from Ks), exp2+mask in regs,
// P feeds PV directly as K=16 A-operand (NO P LDS round-trip), V B-frags
// ds_read_b64 from Vts. 1 coalesced mask word per iter. 2 barriers/iter.
__global__ __launch_bounds__(256) void flash(const __hip_bfloat16* __restrict__ Q,
                                             const __hip_bfloat16* __restrict__ K,
                                             const __hip_bfloat16* __restrict__ Vt,
                                             const unsigned long long* __restrict__ Mbt,
                                             __hip_bfloat16* __restrict__ Y) {
    constexpr int LDT = 72;
    __shared__ __hip_bfloat16 Ks[64 * LDT];    // [key][d]
    __shared__ __hip_bfloat16 Vts[64 * LDT];   // [d][key]

    const int L = blockIdx.x;
    const int b = L & 7, qt = (L >> 3) & 15, h = L >> 7;
    const int bh = b * 8 + h;
    const int tid = threadIdx.x, w = tid >> 6, lane = tid & 63;
    const int lcol = lane & 15, lq = lane >> 4;

    const __hip_bfloat16* Qp = Q + ((long)bh * 1024 + qt * 64 + w * 16 + lcol) * 64 + lq * 8;
    const __hip_bfloat16* Kg = K + (long)bh * 2048 * 64;
    const __hip_bfloat16* Vg = Vt + (long)bh * 64 * 2048;
    const unsigned long long* Mp = Mbt + (long)b * 32 * 1024 + qt * 64 + w * 16 + lcol;

    // Q B-frags (wave's 16 q rows), pre-scaled by 0.125*log2e
    v8bf bq0 = *(const v8bf*)(Qp);
    v8bf bq1 = *(const v8bf*)(Qp + 32);

    f32x4 O[4] = {};
    float lsum = 0.f;

    for (int kt = 0; kt < 32; kt++) {
        // mask word for (q = this lane's row, keys kt*64+[0,64)) — coalesced
        unsigned long long mword = Mp[(long)kt * 1024];
        // stage K tile (contiguous 8 KB) and V^T tile (64 rows x 128 B)
        const uint4* ksrc = (const uint4*)(Kg + kt * 64 * 64);
#pragma unroll
        for (int i = 0; i < 2; i++) {
            int u = tid + i * 256, r = u >> 3, part = u & 7;
            *(uint4*)&Ks[r * LDT + part * 8] = ksrc[u];
        }
#pragma unroll
        for (int i = 0; i < 2; i++) {
            int u = tid + i * 256, dh = u >> 3, part = u & 7;
            *(uint4*)&Vts[dh * LDT + part * 8] = *(const uint4*)(Vg + (long)dh * 2048 + kt * 64 + part * 8);
        }
        __syncthreads();

#pragma unroll
        for (int nt = 0; nt < 4; nt++) {
            // S^T[key][q]: A = K rows (m=key=nt*16+lcol, k=d), B = Q
            v8bf ak0 = *(const v8bf*)&Ks[(nt * 16 + lcol) * LDT + lq * 8];
            v8bf ak1 = *(const v8bf*)&Ks[(nt * 16 + lcol) * LDT + 32 + lq * 8];
            f32x4 st = {};
            st = __builtin_amdgcn_mfma_f32_16x16x32_bf16(ak0, bq0, st, 0, 0, 0);
            st = __builtin_amdgcn_mfma_f32_16x16x32_bf16(ak1, bq1, st, 0, 0, 0);
            // mask nibble for (q=lcol-row, keys nt*16+lq*4+[0,4))
            unsigned int nib = (unsigned int)(mword >> (nt * 16 + lq * 4)) & 0xFu;
            float e0 = ((nib >> 0) & 1u) ? 0.f : __builtin_amdgcn_exp2f(fminf(st[0], 57.f));
            float e1 = ((nib >> 1) & 1u) ? 0.f : __builtin_amdgcn_exp2f(fminf(st[1], 57.f));
            float e2 = ((nib >> 2) & 1u) ? 0.f : __builtin_amdgcn_exp2f(fminf(st[2], 57.f));
            float e3 = ((nib >> 3) & 1u) ? 0.f : __builtin_amdgcn_exp2f(fminf(st[3], 57.f));
            lsum += (e0 + e1) + (e2 + e3);
            // pack P: element j = key nt*16+lq*4+j — already K=16 A-layout
            __hip_bfloat162 lo = __float22bfloat162_rn(make_float2(e0, e1));
            __hip_bfloat162 hi = __float22bfloat162_rn(make_float2(e2, e3));
            uint2 pku;
            __builtin_memcpy(&pku.x, &lo, 4);
            __builtin_memcpy(&pku.y, &hi, 4);
            v4s pa = __builtin_bit_cast(v4s, pku);
            // PV: O[q][d] += P[q][key16] * V[key16][d]; B-frags from Vts
#pragma unroll
            for (int nd = 0; nd < 4; nd++) {
                v4s bv = *(const v4s*)&Vts[(nd * 16 + lcol) * LDT + nt * 16 + lq * 4];
                O[nd] = mfma16x16x16bf(pa, bv, O[nd]);
            }
        }
        __syncthreads();
    }

    // row-sum: reduce over lq groups (lanes sharing lcol)
    float s = lsum;
    s += __shfl_xor(s, 16);
    s += __shfl_xor(s, 32);
    // O C-layout rows are q = lq*4 + r; fetch matching 1/sum via shuffle
    float inv[4];
#pragma unroll
    for (int r = 0; r < 4; r++) inv[r] = 1.f / __shfl(s, lq * 4 + r);

    __hip_bfloat16* Yp = Y + ((long)b * 1024 + qt * 64 + w * 16) * 512 + h * 64 + lcol;
#pragma unroll
    for (int nd = 0; nd < 4; nd++)
#pragma unroll
        for (int r = 0; r < 4; r++)
            Yp[(long)(lq * 4 + r) * 512 + nd * 16] = __float2bfloat16(O[nd][r] * inv[r]);
}

// ---- launch -------------------------------------------------------------
extern "C" void kernel_launch(void* const* d_in, const int* in_sizes, int n_in,
                              void* d_out, int out_size, void* d_ws, size_t ws_size,
                              hipStream_t stream) {
    const float* x = (const float*)d_in[0];
    const float* c = (const float*)d_in[1];
    const int* mask = (const int*)d_in[2];
    const float* Wq = (const float*)d_in[3];
    const float* Wk = (const float*)d_in[4];
    const float* Wv = (const float*)d_in[5];
    const float* Wp = (const float*)d_in[6];

    char* ws = (char*)d_ws;
    __hip_bfloat16* xc  = (__hip_bfloat16*)(ws);                 // 16 MB (dead after gemm_qkv)
    __hip_bfloat16* Wbf = (__hip_bfloat16*)(ws + 16777216);      //  2 MB
    __hip_bfloat16* Qw  = (__hip_bfloat16*)(ws + 18874368);      //  8 MB
    __hip_bfloat16* Kw  = (__hip_bfloat16*)(ws + 27262976);      // 16 MB
    __hip_bfloat16* Vtw = (__hip_bfloat16*)(ws + 44040192);      // 16 MB
    __hip_bfloat16* Yb  = (__hip_bfloat16*)(ws + 60817408);      //  8 MB
    unsigned long long* Mbp = (unsigned long long*)(ws);         //  2 MB, aliases dead xc

    cvt_xcw<<<9216, 256, 0, stream>>>(x, c, Wq, Wk, Wv, Wp, xc, Wbf);
    gemm_qkv<<<dim3(128, 12), 256, 0, stream>>>(xc, Wbf, Qw, Kw, Vtw);
    cvt_mask<<<16384, 256, 0, stream>>>(mask, Mbp);   // after gemm_qkv: overwrites xc
    flash<<<1024, 256, 0, stream>>>(Qw, Kw, Vtw, Mbp, Yb);
    gemm_out<<<dim3(64, 4), 256, 0, stream>>>(Yb, Wbf + 3 * 262144, (float*)d_out);
}